// Round 1
// baseline (684.239 us; speedup 1.0000x reference)
//
#include <hip/hip_runtime.h>

// Problem constants (fixed by the reference)
#define N_IMG 8
#define C_CLS 19
#define H_DIM 512
#define W_DIM 1024
#define HW (H_DIM * W_DIM)              // 524288 pixels per image
#define TOTAL_ELEMS (N_IMG * C_CLS * HW)
#define RATIO 0.2f

#define BLOCKS_PER_IMG 128
#define BLOCK_THREADS 256

// Pass 1: per-image, per-class sum of p^2 (Q) and argmax histogram (Hist),
// single pass over the input. One block row per image (blockIdx.y = n).
__global__ __launch_bounds__(BLOCK_THREADS) void iw_pass1(
    const float* __restrict__ in,   // (N, C, H, W)
    float* __restrict__ Q,          // [N_IMG * C_CLS], pre-zeroed
    int* __restrict__ Hist)         // [N_IMG * C_CLS], pre-zeroed
{
    const int n = blockIdx.y;
    const float* base = in + (size_t)n * C_CLS * HW;

    float q[C_CLS];
    int   hc[C_CLS];
#pragma unroll
    for (int c = 0; c < C_CLS; ++c) { q[c] = 0.0f; hc[c] = 0; }

    const int stride = gridDim.x * blockDim.x;           // 32768 -> 16 iters exactly
    for (int i = blockIdx.x * blockDim.x + threadIdx.x; i < HW; i += stride) {
        float x[C_CLS];
#pragma unroll
        for (int c = 0; c < C_CLS; ++c)
            x[c] = base[(size_t)c * HW + i];             // coalesced per channel

        // argmax (first index on ties, matching jnp.argmax) and max
        float m = x[0];
        int   am = 0;
#pragma unroll
        for (int c = 1; c < C_CLS; ++c) {
            if (x[c] > m) { m = x[c]; am = c; }
        }

        // softmax denom and per-class e^{2(x-m)}
        float S = 0.0f;
#pragma unroll
        for (int c = 0; c < C_CLS; ++c) {
            float e = __expf(x[c] - m);
            S += e;
            x[c] = e * e;                                // reuse regs: e^2
        }
        float inv = 1.0f / (S * S);                      // p_c^2 = e2 * inv

#pragma unroll
        for (int c = 0; c < C_CLS; ++c) {
            q[c] = fmaf(x[c], inv, q[c]);
            hc[c] += (am == c) ? 1 : 0;                  // static idx: no scratch
        }
    }

    // wave-level butterfly reduction (64 lanes), then lane 0 -> global atomics
#pragma unroll
    for (int c = 0; c < C_CLS; ++c) {
        float v  = q[c];
        int   hv = hc[c];
#pragma unroll
        for (int off = 32; off > 0; off >>= 1) {
            v  += __shfl_xor(v, off, 64);
            hv += __shfl_xor(hv, off, 64);
        }
        q[c] = v; hc[c] = hv;
    }
    if ((threadIdx.x & 63) == 0) {
#pragma unroll
        for (int c = 0; c < C_CLS; ++c) {
            atomicAdd(&Q[n * C_CLS + c], q[c]);
            atomicAdd(&Hist[n * C_CLS + c], hc[c]);
        }
    }
}

// Pass 2: weights from histogram, dot with Q, write scalar mean loss.
__global__ __launch_bounds__(64) void iw_pass2(
    const float* __restrict__ Q,
    const int* __restrict__ Hist,
    float* __restrict__ out)
{
    const int t = threadIdx.x;
    float loss = 0.0f;
    if (t < N_IMG) {
        float h[C_CLS];
        float hs = 0.0f;
#pragma unroll
        for (int c = 0; c < C_CLS; ++c) {
            float v = (float)Hist[t * C_CLS + c];
            v = (v == 0.0f) ? 1.0f : v;                  // hist[hist==0] = 1
            h[c] = v;
            hs += v;                                     // sum AFTER replacement
        }
#pragma unroll
        for (int c = 0; c < C_CLS; ++c) {
            float w = powf(hs / h[c], RATIO);
            loss = fmaf(w, Q[t * C_CLS + c], loss);
        }
    }
    // reduce the 8 per-image values (lanes 8..63 contribute 0)
    loss += __shfl_xor(loss, 1, 64);
    loss += __shfl_xor(loss, 2, 64);
    loss += __shfl_xor(loss, 4, 64);
    if (t == 0)
        out[0] = -loss / (float)TOTAL_ELEMS;
}

extern "C" void kernel_launch(void* const* d_in, const int* in_sizes, int n_in,
                              void* d_out, int out_size, void* d_ws, size_t ws_size,
                              hipStream_t stream)
{
    const float* in = (const float*)d_in[0];
    float* out = (float*)d_out;

    // workspace layout: Q (float[152]) then Hist (int[152])
    float* Q  = (float*)d_ws;
    int* Hist = (int*)((char*)d_ws + N_IMG * C_CLS * sizeof(float));

    hipMemsetAsync(d_ws, 0, N_IMG * C_CLS * (sizeof(float) + sizeof(int)), stream);

    dim3 grid(BLOCKS_PER_IMG, N_IMG);
    iw_pass1<<<grid, BLOCK_THREADS, 0, stream>>>(in, Q, Hist);
    iw_pass2<<<1, 64, 0, stream>>>(Q, Hist, out);
}

// Round 2
// 432.934 us; speedup vs baseline: 1.5805x; 1.5805x over previous
//
#include <hip/hip_runtime.h>

// Problem constants (fixed by the reference)
#define N_IMG 8
#define C_CLS 19
#define H_DIM 512
#define W_DIM 1024
#define HW (H_DIM * W_DIM)              // 524288 pixels per image
#define HW4 (HW / 4)                    // 131072 float4 groups per channel
#define TOTAL_ELEMS (N_IMG * C_CLS * HW)
#define RATIO 0.2f

#define BLOCKS_X 256                    // blocks per image
#define BLOCK_THREADS 256
#define ITERS 2                         // HW4 / (BLOCKS_X * BLOCK_THREADS) == 2 exactly

__device__ __forceinline__ float& f4c(float4& v, int k) {
    return reinterpret_cast<float*>(&v)[k];   // k is compile-time after unroll
}

// Pass 1: per-image per-class sum of p^2 (Q) and argmax histogram (Hist),
// single pass, float4-vectorized loads (19 independent dwordx4 in flight).
__global__ __launch_bounds__(BLOCK_THREADS) void iw_pass1(
    const float* __restrict__ in,   // (N, C, H, W)
    float* __restrict__ Q,          // [N_IMG * C_CLS], pre-zeroed
    int* __restrict__ Hist)         // [N_IMG * C_CLS], pre-zeroed
{
    const int n = blockIdx.y;
    const float4* base4 = reinterpret_cast<const float4*>(in + (size_t)n * C_CLS * HW);

    float q[C_CLS];
    int   hc[C_CLS];
#pragma unroll
    for (int c = 0; c < C_CLS; ++c) { q[c] = 0.0f; hc[c] = 0; }

    const int tid = threadIdx.x;
    int i = blockIdx.x * BLOCK_THREADS + tid;

#pragma unroll 1   // keep ONE iteration's live set; rely on TLP across waves
    for (int it = 0; it < ITERS; ++it, i += BLOCKS_X * BLOCK_THREADS) {
        float4 x4[C_CLS];
        // 19 independent 16B/lane loads, issued back-to-back
#pragma unroll
        for (int c = 0; c < C_CLS; ++c)
            x4[c] = base4[(size_t)c * HW4 + i];

#pragma unroll
        for (int k = 0; k < 4; ++k) {
            // argmax (first index on ties, matching jnp.argmax) + max
            float m = f4c(x4[0], k);
            int   am = 0;
#pragma unroll
            for (int c = 1; c < C_CLS; ++c) {
                float xc = f4c(x4[c], k);
                if (xc > m) { m = xc; am = c; }
            }
            // softmax denom; overwrite component k in place with e^2
            float S = 0.0f;
#pragma unroll
            for (int c = 0; c < C_CLS; ++c) {
                float e = __expf(f4c(x4[c], k) - m);
                S += e;
                f4c(x4[c], k) = e * e;
            }
            float inv = 1.0f / (S * S);      // p_c^2 = e^2 * inv
#pragma unroll
            for (int c = 0; c < C_CLS; ++c) {
                q[c] = fmaf(f4c(x4[c], k), inv, q[c]);
                hc[c] += (am == c) ? 1 : 0;
            }
        }
    }

    // wave butterfly reduction (64 lanes)
#pragma unroll
    for (int c = 0; c < C_CLS; ++c) {
        float v  = q[c];
        int   hv = hc[c];
#pragma unroll
        for (int off = 32; off > 0; off >>= 1) {
            v  += __shfl_xor(v, off, 64);
            hv += __shfl_xor(hv, off, 64);
        }
        q[c] = v; hc[c] = hv;
    }

    // cross-wave LDS reduction -> one atomic set per block
    __shared__ float qs[4 * C_CLS];
    __shared__ int   hs[4 * C_CLS];
    const int wave = tid >> 6, lane = tid & 63;
    if (lane == 0) {
#pragma unroll
        for (int c = 0; c < C_CLS; ++c) {
            qs[wave * C_CLS + c] = q[c];
            hs[wave * C_CLS + c] = hc[c];
        }
    }
    __syncthreads();
    if (tid < C_CLS) {
        float s  = qs[tid] + qs[C_CLS + tid] + qs[2 * C_CLS + tid] + qs[3 * C_CLS + tid];
        int   hv = hs[tid] + hs[C_CLS + tid] + hs[2 * C_CLS + tid] + hs[3 * C_CLS + tid];
        atomicAdd(&Q[n * C_CLS + tid], s);
        atomicAdd(&Hist[n * C_CLS + tid], hv);
    }
}

// Pass 2: weights from histogram, dot with Q, write scalar mean loss.
__global__ __launch_bounds__(64) void iw_pass2(
    const float* __restrict__ Q,
    const int* __restrict__ Hist,
    float* __restrict__ out)
{
    const int t = threadIdx.x;
    float loss = 0.0f;
    if (t < N_IMG) {
        float h[C_CLS];
        float hs = 0.0f;
#pragma unroll
        for (int c = 0; c < C_CLS; ++c) {
            float v = (float)Hist[t * C_CLS + c];
            v = (v == 0.0f) ? 1.0f : v;                  // hist[hist==0] = 1
            h[c] = v;
            hs += v;                                     // sum AFTER replacement
        }
#pragma unroll
        for (int c = 0; c < C_CLS; ++c) {
            float w = powf(hs / h[c], RATIO);
            loss = fmaf(w, Q[t * C_CLS + c], loss);
        }
    }
    // reduce the 8 per-image values (lanes 8..63 contribute 0)
    loss += __shfl_xor(loss, 1, 64);
    loss += __shfl_xor(loss, 2, 64);
    loss += __shfl_xor(loss, 4, 64);
    if (t == 0)
        out[0] = -loss / (float)TOTAL_ELEMS;
}

extern "C" void kernel_launch(void* const* d_in, const int* in_sizes, int n_in,
                              void* d_out, int out_size, void* d_ws, size_t ws_size,
                              hipStream_t stream)
{
    const float* in = (const float*)d_in[0];
    float* out = (float*)d_out;

    // workspace layout: Q (float[152]) then Hist (int[152])
    float* Q  = (float*)d_ws;
    int* Hist = (int*)((char*)d_ws + N_IMG * C_CLS * sizeof(float));

    hipMemsetAsync(d_ws, 0, N_IMG * C_CLS * (sizeof(float) + sizeof(int)), stream);

    dim3 grid(BLOCKS_X, N_IMG);
    iw_pass1<<<grid, BLOCK_THREADS, 0, stream>>>(in, Q, Hist);
    iw_pass2<<<1, 64, 0, stream>>>(Q, Hist, out);
}

// Round 3
// 422.078 us; speedup vs baseline: 1.6211x; 1.0257x over previous
//
#include <hip/hip_runtime.h>

// Problem constants (fixed by the reference)
#define N_IMG 8
#define C_CLS 19
#define H_DIM 512
#define W_DIM 1024
#define HW (H_DIM * W_DIM)              // 524288 pixels per image
#define HW4 (HW / 4)                    // 131072 float4 groups per channel
#define TOTAL_ELEMS (N_IMG * C_CLS * HW)
#define RATIO 0.2f

#define BLOCKS_X 512                    // blocks per image: 512*256 = HW4 exactly
#define BLOCK_THREADS 256

__device__ __forceinline__ float& f4c(float4& v, int k) {
    return reinterpret_cast<float*>(&v)[k];   // k is compile-time after unroll
}

// Pass 1: per-image per-class sum of p^2 (Q) and argmax histogram (Hist),
// single pass. Each thread: ONE float4 per channel (no loop -> no WAR stall
// between load bursts). Histogram via ballot (SGPR, scalar pipe) instead of
// 19 per-thread int VGPRs. __launch_bounds__(256,4) pins VGPR<=128 so we get
// 4 waves/SIMD.
__global__ __launch_bounds__(BLOCK_THREADS, 4) void iw_pass1(
    const float* __restrict__ in,   // (N, C, H, W)
    float* __restrict__ Q,          // [N_IMG * C_CLS], pre-zeroed
    int* __restrict__ Hist)         // [N_IMG * C_CLS], pre-zeroed
{
    const int n = blockIdx.y;
    const float4* base4 = reinterpret_cast<const float4*>(in + (size_t)n * C_CLS * HW);
    const int i = blockIdx.x * BLOCK_THREADS + threadIdx.x;   // float4 index in plane

    // 19 independent 16B/lane loads, all in flight together
    float4 x4[C_CLS];
#pragma unroll
    for (int c = 0; c < C_CLS; ++c)
        x4[c] = base4[(size_t)c * HW4 + i];

    float q[C_CLS];
#pragma unroll
    for (int c = 0; c < C_CLS; ++c) q[c] = 0.0f;

    int hw_cnt[C_CLS];      // wave-uniform ballot counts (expect SGPR)
#pragma unroll
    for (int c = 0; c < C_CLS; ++c) hw_cnt[c] = 0;

#pragma unroll
    for (int k = 0; k < 4; ++k) {
        // argmax (first index on ties, matching jnp.argmax) + max
        float m = f4c(x4[0], k);
        int   am = 0;
#pragma unroll
        for (int c = 1; c < C_CLS; ++c) {
            float xc = f4c(x4[c], k);
            if (xc > m) { m = xc; am = c; }
        }
        // histogram via wave ballot: wave-uniform counts, scalar registers
#pragma unroll
        for (int c = 0; c < C_CLS; ++c)
            hw_cnt[c] += (int)__popcll(__ballot(am == c));

        // softmax denom; overwrite component k in place with e^2
        float S = 0.0f;
#pragma unroll
        for (int c = 0; c < C_CLS; ++c) {
            float e = __expf(f4c(x4[c], k) - m);
            S += e;
            f4c(x4[c], k) = e * e;
        }
        float inv = 1.0f / (S * S);      // p_c^2 = e^2 * inv
#pragma unroll
        for (int c = 0; c < C_CLS; ++c)
            q[c] = fmaf(f4c(x4[c], k), inv, q[c]);
    }

    // wave butterfly reduction of q (64 lanes)
#pragma unroll
    for (int c = 0; c < C_CLS; ++c) {
        float v = q[c];
#pragma unroll
        for (int off = 32; off > 0; off >>= 1)
            v += __shfl_xor(v, off, 64);
        q[c] = v;
    }

    // cross-wave LDS reduction -> one atomic set per block
    __shared__ float qs[4 * C_CLS];
    __shared__ int   hs[4 * C_CLS];
    const int tid = threadIdx.x;
    const int wave = tid >> 6, lane = tid & 63;
    if (lane == 0) {
#pragma unroll
        for (int c = 0; c < C_CLS; ++c) {
            qs[wave * C_CLS + c] = q[c];
            hs[wave * C_CLS + c] = hw_cnt[c];
        }
    }
    __syncthreads();
    if (tid < C_CLS) {
        float s  = qs[tid] + qs[C_CLS + tid] + qs[2 * C_CLS + tid] + qs[3 * C_CLS + tid];
        int   hv = hs[tid] + hs[C_CLS + tid] + hs[2 * C_CLS + tid] + hs[3 * C_CLS + tid];
        atomicAdd(&Q[n * C_CLS + tid], s);
        atomicAdd(&Hist[n * C_CLS + tid], hv);
    }
}

// Pass 2: weights from histogram, dot with Q, write scalar mean loss.
__global__ __launch_bounds__(64) void iw_pass2(
    const float* __restrict__ Q,
    const int* __restrict__ Hist,
    float* __restrict__ out)
{
    const int t = threadIdx.x;
    float loss = 0.0f;
    if (t < N_IMG) {
        float h[C_CLS];
        float hs = 0.0f;
#pragma unroll
        for (int c = 0; c < C_CLS; ++c) {
            float v = (float)Hist[t * C_CLS + c];
            v = (v == 0.0f) ? 1.0f : v;                  // hist[hist==0] = 1
            h[c] = v;
            hs += v;                                     // sum AFTER replacement
        }
#pragma unroll
        for (int c = 0; c < C_CLS; ++c) {
            float w = powf(hs / h[c], RATIO);
            loss = fmaf(w, Q[t * C_CLS + c], loss);
        }
    }
    // reduce the 8 per-image values (lanes 8..63 contribute 0)
    loss += __shfl_xor(loss, 1, 64);
    loss += __shfl_xor(loss, 2, 64);
    loss += __shfl_xor(loss, 4, 64);
    if (t == 0)
        out[0] = -loss / (float)TOTAL_ELEMS;
}

extern "C" void kernel_launch(void* const* d_in, const int* in_sizes, int n_in,
                              void* d_out, int out_size, void* d_ws, size_t ws_size,
                              hipStream_t stream)
{
    const float* in = (const float*)d_in[0];
    float* out = (float*)d_out;

    // workspace layout: Q (float[152]) then Hist (int[152])
    float* Q  = (float*)d_ws;
    int* Hist = (int*)((char*)d_ws + N_IMG * C_CLS * sizeof(float));

    hipMemsetAsync(d_ws, 0, N_IMG * C_CLS * (sizeof(float) + sizeof(int)), stream);

    dim3 grid(BLOCKS_X, N_IMG);
    iw_pass1<<<grid, BLOCK_THREADS, 0, stream>>>(in, Q, Hist);
    iw_pass2<<<1, 64, 0, stream>>>(Q, Hist, out);
}